// Round 1
// baseline (122.905 us; speedup 1.0000x reference)
//
#include <hip/hip_runtime.h>

#define BB 1024
#define NN 128
#define VV 200
#define HH 400

__device__ inline float wave_sum(float v){
  for (int o=32;o>0;o>>=1) v += __shfl_down(v,o);
  return v;
}
__device__ inline float wave_max(float v){
  for (int o=32;o>0;o>>=1) v = fmaxf(v, __shfl_down(v,o));
  return v;
}

// ---------------- Kernel 1: per-b attention (algebraically reduced) ----------
__global__ __launch_bounds__(256) void attn_kernel(
    const float* __restrict__ merged,
    const float* __restrict__ Wq_aug, const float* __restrict__ bq_aug,
    const float* __restrict__ Wk_aug, const float* __restrict__ bk_aug,
    const float* __restrict__ Wv_aug, const float* __restrict__ bv_aug,
    const float* __restrict__ Wq_o,  const float* __restrict__ bq_o,
    const float* __restrict__ Wk_o,  const float* __restrict__ bk_o,
    const float* __restrict__ Wv_o,  const float* __restrict__ bv_o,
    float* __restrict__ t_buf)
{
  int b = blockIdx.x;
  int tid = threadIdx.x;
  int wv = tid>>6, lane = tid&63;
  const float* base = merged + (size_t)b*NN*15;

  __shared__ float q_aug[VV], q_o[VV];
  __shared__ float wkq_aug[14], wkq_o[7];
  __shared__ float qbk_aug_s, qbk_o_s;
  __shared__ float kv[NN*14];
  __shared__ float s_aug[NN], s_o[NN];
  __shared__ float wgt[3][NN];
  __shared__ unsigned char msk[3][NN];
  __shared__ float wf[3][14];
  __shared__ int anyf[3];
  __shared__ int w0cnt;

  float sub_bus = base[0];
  float sub_loc = base[2];

  // q projections (ego7[0] == 0 after the sub_bus subtraction)
  if (tid < VV) {
    float qa = bq_aug[tid], qo = bq_o[tid];
    for (int j=1;j<7;j++){
      float e = base[j];
      qa += e * Wq_aug[j*VV+tid];
      qo += e * Wq_o[j*VV+tid];
    }
    q_aug[tid]=qa; q_o[tid]=qo;
  }
  __syncthreads();

  // fold Wk into q: 23 reductions of length 200
  for (int r=wv; r<23; r+=4){
    const float* coef; const float* qv;
    if (r<14)      { coef = Wk_aug + r*VV;      qv = q_aug; }
    else if (r==14){ coef = bk_aug;             qv = q_aug; }
    else if (r<22) { coef = Wk_o + (r-15)*VV;   qv = q_o;   }
    else           { coef = bk_o;               qv = q_o;   }
    float p=0;
    for (int d=lane; d<VV; d+=64) p += coef[d]*qv[d];
    p = wave_sum(p);
    if (lane==0){
      if (r<14) wkq_aug[r]=p;
      else if (r==14) qbk_aug_s=p;
      else if (r<22) wkq_o[r-15]=p;
      else qbk_o_s=p;
    }
  }
  __syncthreads();

  // per-n scores & masks
  const float scale = 0.07071067811865475f; // 1/sqrt(200)
  bool f0=false;
  int prior = 0;
  if (tid < NN){
    float m[15];
    for (int i=0;i<15;i++) m[i] = base[tid*15+i];
    m[0]-=sub_bus; m[7]-=sub_bus;
    for (int f=0;f<14;f++) kv[tid*14+f]=m[f];
    float flag=m[14], loc=m[2];
    f0 = (flag==0.0f);
    bool um = (loc<sub_loc) && (flag==1.0f);
    bool dm = (loc>sub_loc) && (flag==1.0f);
    float sa = qbk_aug_s, so = qbk_o_s;
    for (int f=0;f<14;f++) sa += m[f]*wkq_aug[f];
    for (int f=0;f<7;f++)  so += m[f]*wkq_o[f];
    s_aug[tid]=sa*scale; s_o[tid]=so*scale;
    msk[0][tid]=um; msk[1][tid]=dm;
    unsigned long long bal = __ballot(f0);
    prior = __popcll(bal & ((1ull<<lane)-1ull));
    if (tid==0) w0cnt = __popcll(bal);
  }
  __syncthreads();
  if (tid < NN){
    int ptot = prior + (wv==1 ? w0cnt : 0);
    msk[2][tid] = (unsigned char)(f0 && (ptot>0));
  }
  __syncthreads();

  // masked softmax, one wave per mask
  if (wv < 3){
    const float* sarr = (wv==2)? s_o : s_aug;
    float mx=-3e38f;
    for (int i=lane;i<NN;i+=64) if (msk[wv][i]) mx = fmaxf(mx, sarr[i]);
    mx = wave_max(mx);
    mx = __shfl(mx, 0);
    float sum=0;
    for (int i=lane;i<NN;i+=64) if (msk[wv][i]) sum += expf(sarr[i]-mx);
    sum = wave_sum(sum);
    sum = __shfl(sum, 0);
    int any = (mx > -1e38f) ? 1 : 0;
    float inv = any ? 1.0f/sum : 0.0f;
    for (int i=lane;i<NN;i+=64)
      wgt[wv][i] = msk[wv][i] ? expf(sarr[i]-mx)*inv : 0.0f;
    if (lane==0) anyf[wv]=any;
  }
  __syncthreads();

  // weighted feature sums: 35 reductions of length 128
  for (int r=wv; r<35; r+=4){
    int mi, f;
    if (r<14){mi=0;f=r;} else if (r<28){mi=1;f=r-14;} else {mi=2;f=r-28;}
    float p=0;
    for (int n=lane;n<NN;n+=64) p += wgt[mi][n]*kv[n*14+f];
    p=wave_sum(p);
    if (lane==0) wf[mi][f]=p;
  }
  __syncthreads();

  // project to V=200 through Wv
  if (tid < VV){
    float uv=bv_aug[tid], dv=bv_aug[tid], ov=bv_o[tid];
    for (int f=0;f<14;f++){
      float w = Wv_aug[f*VV+tid];
      uv += wf[0][f]*w;
      dv += wf[1][f]*w;
    }
    for (int f=0;f<7;f++) ov += wf[2][f]*Wv_o[f*VV+tid];
    if (!anyf[0]) uv=0.0f;
    if (!anyf[1]) dv=0.0f;
    if (!anyf[2]) ov=0.0f;
    float* tb = t_buf + (size_t)b*600;
    tb[tid]=uv; tb[200+tid]=dv; tb[400+tid]=ov;
  }
}

// ---------------- Kernel 2: BN stats over batch ------------------------------
__global__ __launch_bounds__(256) void bn_stats(const float* __restrict__ t_buf,
    float* __restrict__ mean_out, float* __restrict__ rstd_out)
{
  int c = blockIdx.x; int tid=threadIdx.x; int wv=tid>>6, lane=tid&63;
  float s=0, s2=0;
  for (int b=tid;b<BB;b+=256){ float v=t_buf[(size_t)b*600+c]; s+=v; s2+=v*v; }
  s = wave_sum(s); s2 = wave_sum(s2);
  __shared__ float ls[4], ls2[4];
  if (lane==0){ ls[wv]=s; ls2[wv]=s2; }
  __syncthreads();
  if (tid==0){
    float S=ls[0]+ls[1]+ls[2]+ls[3];
    float S2=ls2[0]+ls2[1]+ls2[2]+ls2[3];
    float mean = S*(1.0f/BB);
    float var = S2*(1.0f/BB) - mean*mean;
    mean_out[c]=mean;
    rstd_out[c]=rsqrtf(var+1e-5f);
  }
}

// ---------------- Kernel 3: ego MLP -> Q1 (4 b per block) --------------------
__global__ __launch_bounds__(256) void mlp_q(
    const float* __restrict__ x, const float* __restrict__ a,
    const float* __restrict__ W0, const float* __restrict__ b0,
    const float* __restrict__ W1, const float* __restrict__ b1,
    const float* __restrict__ W2, const float* __restrict__ b2,
    float* __restrict__ Q1buf, float* __restrict__ out)
{
  int bb = blockIdx.x*4;
  int tid=threadIdx.x, wv=tid>>6, lane=tid&63;
  __shared__ float h1[4][HH];
  __shared__ float h2[4][HH];
  __shared__ float ego[4][4];
  if (tid<16){
    int bl=tid>>2, j=tid&3;
    int b=bb+bl;
    ego[bl][j] = (j<3) ? x[((size_t)b*NN)*8 + 4 + j] : a[b];
  }
  __syncthreads();
  for (int j=tid;j<HH;j+=256){
    float w0j[4];
    for (int i=0;i<4;i++) w0j[i]=W0[i*HH+j];
    for (int bl=0;bl<4;bl++){
      float v = b0[j];
      for (int i=0;i<4;i++) v += ego[bl][i]*w0j[i];
      h1[bl][j] = fmaxf(v, 0.0f);
    }
  }
  __syncthreads();
  for (int j=tid;j<HH;j+=256){
    float a0=b1[j], a1=a0, a2=a0, a3=a0;
    for (int i=0;i<HH;i++){
      float w=W1[i*HH+j];
      a0 += h1[0][i]*w; a1 += h1[1][i]*w; a2 += h1[2][i]*w; a3 += h1[3][i]*w;
    }
    h2[0][j]=fmaxf(a0,0.f); h2[1][j]=fmaxf(a1,0.f);
    h2[2][j]=fmaxf(a2,0.f); h2[3][j]=fmaxf(a3,0.f);
  }
  __syncthreads();
  float p=0;
  for (int j=lane;j<HH;j+=64) p += h2[wv][j]*W2[j];
  p = wave_sum(p);
  if (lane==0){
    float q = p + b2[0];
    Q1buf[bb+wv]=q;
    out[bb+wv]=q;
  }
}

// ---------------- Kernel 4: BN apply + heads + outputs (4 b per block) -------
__global__ __launch_bounds__(256) void heads_kernel(
    const float* __restrict__ t_buf, const float* __restrict__ mean_in,
    const float* __restrict__ rstd_in,
    const float* __restrict__ bn_g, const float* __restrict__ bn_b,
    const float* __restrict__ W3, const float* __restrict__ b3,
    const float* __restrict__ W4, const float* __restrict__ b4,
    const float* __restrict__ Q1buf, float* __restrict__ out)
{
  int bb = blockIdx.x*4;
  int tid=threadIdx.x, wv=tid>>6, lane=tid&63;
  __shared__ float tn[4][600];
  __shared__ float h[4][1200];
  __shared__ float headv[4][6];
  for (int idx=tid; idx<2400; idx+=256){
    int bl=idx/600, c=idx%600, v=c%200;
    tn[bl][c] = bn_g[v]*(t_buf[(size_t)(bb+bl)*600+c]-mean_in[c])*rstd_in[c]+bn_b[v];
  }
  __syncthreads();
  for (int p=tid;p<1200;p+=256){
    int k=p/200; int koff=(k>>1)*200; int g=p-k*200;
    float a0=b3[p],a1=a0,a2=a0,a3=a0;
    const float* w3p = W3 + (size_t)k*40000 + g;
    for (int v=0;v<200;v++){
      float w = w3p[(size_t)v*200];
      a0 += tn[0][koff+v]*w;
      a1 += tn[1][koff+v]*w;
      a2 += tn[2][koff+v]*w;
      a3 += tn[3][koff+v]*w;
    }
    h[0][p] = a0>0.f?a0:(expf(a0)-1.0f);
    h[1][p] = a1>0.f?a1:(expf(a1)-1.0f);
    h[2][p] = a2>0.f?a2:(expf(a2)-1.0f);
    h[3][p] = a3>0.f?a3:(expf(a3)-1.0f);
  }
  __syncthreads();
  for (int k=0;k<6;k++){
    float p2=0;
    for (int g=lane;g<200;g+=64) p2 += h[wv][k*200+g]*W4[k*200+g];
    p2 = wave_sum(p2);
    if (lane==0) headv[wv][k]=p2+b4[k];
  }
  __syncthreads();
  if (tid<4){
    int b=bb+tid;
    float A1=headv[tid][0]+headv[tid][2]+headv[tid][4];
    float A2=headv[tid][1]+headv[tid][3]+headv[tid][5];
    float q=Q1buf[b];
    out[BB+b]=A2;
    out[2*BB+b]=q+A1;
    out[3*BB+b]=q+A2;
  }
  if (bb==0 && tid==4) out[4*BB]=0.0f;
}

extern "C" void kernel_launch(void* const* d_in, const int* in_sizes, int n_in,
                              void* d_out, int out_size, void* d_ws, size_t ws_size,
                              hipStream_t stream)
{
  (void)in_sizes; (void)n_in; (void)out_size; (void)ws_size;
  const float* merged=(const float*)d_in[0];
  const float* x     =(const float*)d_in[1];
  const float* a     =(const float*)d_in[2];
  const float* Wq_aug=(const float*)d_in[3];  const float* bq_aug=(const float*)d_in[4];
  const float* Wk_aug=(const float*)d_in[5];  const float* bk_aug=(const float*)d_in[6];
  const float* Wv_aug=(const float*)d_in[7];  const float* bv_aug=(const float*)d_in[8];
  const float* Wq_o  =(const float*)d_in[9];  const float* bq_o  =(const float*)d_in[10];
  const float* Wk_o  =(const float*)d_in[11]; const float* bk_o  =(const float*)d_in[12];
  const float* Wv_o  =(const float*)d_in[13]; const float* bv_o  =(const float*)d_in[14];
  const float* bn_g  =(const float*)d_in[15]; const float* bn_b  =(const float*)d_in[16];
  const float* W3    =(const float*)d_in[17]; const float* b3    =(const float*)d_in[18];
  const float* W4    =(const float*)d_in[19]; const float* b4    =(const float*)d_in[20];
  const float* W0    =(const float*)d_in[21]; const float* b0    =(const float*)d_in[22];
  const float* W1    =(const float*)d_in[23]; const float* b1    =(const float*)d_in[24];
  const float* W2    =(const float*)d_in[25]; const float* b2    =(const float*)d_in[26];

  float* out = (float*)d_out;
  float* ws  = (float*)d_ws;
  float* t_buf  = ws;            // 1024*600 = 614400 floats
  float* mean_b = ws + 614400;   // 600
  float* rstd_b = ws + 615000;   // 600
  float* Q1buf  = ws + 615600;   // 1024

  hipLaunchKernelGGL(attn_kernel, dim3(BB), dim3(256), 0, stream, merged,
      Wq_aug,bq_aug,Wk_aug,bk_aug,Wv_aug,bv_aug,
      Wq_o,bq_o,Wk_o,bk_o,Wv_o,bv_o, t_buf);
  hipLaunchKernelGGL(mlp_q, dim3(BB/4), dim3(256), 0, stream,
      x,a,W0,b0,W1,b1,W2,b2, Q1buf, out);
  hipLaunchKernelGGL(bn_stats, dim3(600), dim3(256), 0, stream,
      t_buf, mean_b, rstd_b);
  hipLaunchKernelGGL(heads_kernel, dim3(BB/4), dim3(256), 0, stream,
      t_buf, mean_b, rstd_b, bn_g, bn_b, W3, b3, W4, b4, Q1buf, out);
}

// Round 2
// 83.344 us; speedup vs baseline: 1.4747x; 1.4747x over previous
//
#include <hip/hip_runtime.h>

#define BB 1024
#define NN 128
#define VV 200
#define HH 400

__device__ inline float wave_sum(float v){
  for (int o=32;o>0;o>>=1) v += __shfl_down(v,o);
  return v;
}
__device__ inline float wave_max(float v){
  for (int o=32;o>0;o>>=1) v = fmaxf(v, __shfl_down(v,o));
  return v;
}

// ---------------- Kernel 1: per-b attention (algebraically reduced) ----------
__global__ __launch_bounds__(256) void attn_kernel(
    const float* __restrict__ merged,
    const float* __restrict__ Wq_aug, const float* __restrict__ bq_aug,
    const float* __restrict__ Wk_aug, const float* __restrict__ bk_aug,
    const float* __restrict__ Wv_aug, const float* __restrict__ bv_aug,
    const float* __restrict__ Wq_o,  const float* __restrict__ bq_o,
    const float* __restrict__ Wk_o,  const float* __restrict__ bk_o,
    const float* __restrict__ Wv_o,  const float* __restrict__ bv_o,
    float* __restrict__ t_buf)
{
  int b = blockIdx.x;
  int tid = threadIdx.x;
  int wv = tid>>6, lane = tid&63;
  const float* base = merged + (size_t)b*NN*15;

  __shared__ float q_aug[VV], q_o[VV];
  __shared__ float wkq_aug[14], wkq_o[7];
  __shared__ float qbk_aug_s, qbk_o_s;
  __shared__ float kv[NN*14];
  __shared__ float s_aug[NN], s_o[NN];
  __shared__ float wgt[3][NN];
  __shared__ unsigned char msk[3][NN];
  __shared__ float wf[3][14];
  __shared__ int anyf[3];
  __shared__ int w0cnt;

  float sub_bus = base[0];
  float sub_loc = base[2];

  // q projections (ego7[0] == 0 after the sub_bus subtraction)
  if (tid < VV) {
    float qa = bq_aug[tid], qo = bq_o[tid];
    for (int j=1;j<7;j++){
      float e = base[j];
      qa += e * Wq_aug[j*VV+tid];
      qo += e * Wq_o[j*VV+tid];
    }
    q_aug[tid]=qa; q_o[tid]=qo;
  }
  __syncthreads();

  // fold Wk into q: 23 reductions of length 200
  for (int r=wv; r<23; r+=4){
    const float* coef; const float* qv;
    if (r<14)      { coef = Wk_aug + r*VV;      qv = q_aug; }
    else if (r==14){ coef = bk_aug;             qv = q_aug; }
    else if (r<22) { coef = Wk_o + (r-15)*VV;   qv = q_o;   }
    else           { coef = bk_o;               qv = q_o;   }
    float p=0;
    for (int d=lane; d<VV; d+=64) p += coef[d]*qv[d];
    p = wave_sum(p);
    if (lane==0){
      if (r<14) wkq_aug[r]=p;
      else if (r==14) qbk_aug_s=p;
      else if (r<22) wkq_o[r-15]=p;
      else qbk_o_s=p;
    }
  }
  __syncthreads();

  // per-n scores & masks
  const float scale = 0.07071067811865475f; // 1/sqrt(200)
  bool f0=false;
  int prior = 0;
  if (tid < NN){
    float m[15];
    for (int i=0;i<15;i++) m[i] = base[tid*15+i];
    m[0]-=sub_bus; m[7]-=sub_bus;
    for (int f=0;f<14;f++) kv[tid*14+f]=m[f];
    float flag=m[14], loc=m[2];
    f0 = (flag==0.0f);
    bool um = (loc<sub_loc) && (flag==1.0f);
    bool dm = (loc>sub_loc) && (flag==1.0f);
    float sa = qbk_aug_s, so = qbk_o_s;
    for (int f=0;f<14;f++) sa += m[f]*wkq_aug[f];
    for (int f=0;f<7;f++)  so += m[f]*wkq_o[f];
    s_aug[tid]=sa*scale; s_o[tid]=so*scale;
    msk[0][tid]=um; msk[1][tid]=dm;
    unsigned long long bal = __ballot(f0);
    prior = __popcll(bal & ((1ull<<lane)-1ull));
    if (tid==0) w0cnt = __popcll(bal);
  }
  __syncthreads();
  if (tid < NN){
    int ptot = prior + (wv==1 ? w0cnt : 0);
    msk[2][tid] = (unsigned char)(f0 && (ptot>0));
  }
  __syncthreads();

  // masked softmax, one wave per mask
  if (wv < 3){
    const float* sarr = (wv==2)? s_o : s_aug;
    float mx=-3e38f;
    for (int i=lane;i<NN;i+=64) if (msk[wv][i]) mx = fmaxf(mx, sarr[i]);
    mx = wave_max(mx);
    mx = __shfl(mx, 0);
    float sum=0;
    for (int i=lane;i<NN;i+=64) if (msk[wv][i]) sum += expf(sarr[i]-mx);
    sum = wave_sum(sum);
    sum = __shfl(sum, 0);
    int any = (mx > -1e38f) ? 1 : 0;
    float inv = any ? 1.0f/sum : 0.0f;
    for (int i=lane;i<NN;i+=64)
      wgt[wv][i] = msk[wv][i] ? expf(sarr[i]-mx)*inv : 0.0f;
    if (lane==0) anyf[wv]=any;
  }
  __syncthreads();

  // weighted feature sums: 35 reductions of length 128
  for (int r=wv; r<35; r+=4){
    int mi, f;
    if (r<14){mi=0;f=r;} else if (r<28){mi=1;f=r-14;} else {mi=2;f=r-28;}
    float p=0;
    for (int n=lane;n<NN;n+=64) p += wgt[mi][n]*kv[n*14+f];
    p=wave_sum(p);
    if (lane==0) wf[mi][f]=p;
  }
  __syncthreads();

  // project to V=200 through Wv
  if (tid < VV){
    float uv=bv_aug[tid], dv=bv_aug[tid], ov=bv_o[tid];
    for (int f=0;f<14;f++){
      float w = Wv_aug[f*VV+tid];
      uv += wf[0][f]*w;
      dv += wf[1][f]*w;
    }
    for (int f=0;f<7;f++) ov += wf[2][f]*Wv_o[f*VV+tid];
    if (!anyf[0]) uv=0.0f;
    if (!anyf[1]) dv=0.0f;
    if (!anyf[2]) ov=0.0f;
    float* tb = t_buf + (size_t)b*600;
    tb[tid]=uv; tb[200+tid]=dv; tb[400+tid]=ov;
  }
}

// ---------------- Kernel 2: BN stats over batch (float4, each elem once) -----
__global__ __launch_bounds__(256) void bn_stats(const float* __restrict__ t_buf,
    float* __restrict__ mean_out, float* __restrict__ rstd_out)
{
  int c0 = blockIdx.x*4;          // 150 blocks x 4 channels
  int tid=threadIdx.x; int wv=tid>>6, lane=tid&63;
  float s[4]={0,0,0,0}, s2[4]={0,0,0,0};
  for (int b=tid;b<BB;b+=256){
    float4 v = *reinterpret_cast<const float4*>(t_buf + (size_t)b*600 + c0);
    s[0]+=v.x; s[1]+=v.y; s[2]+=v.z; s[3]+=v.w;
    s2[0]+=v.x*v.x; s2[1]+=v.y*v.y; s2[2]+=v.z*v.z; s2[3]+=v.w*v.w;
  }
  __shared__ float ls[4][4], ls2[4][4];
  for (int c=0;c<4;c++){ s[c]=wave_sum(s[c]); s2[c]=wave_sum(s2[c]); }
  if (lane==0){
    for (int c=0;c<4;c++){ ls[wv][c]=s[c]; ls2[wv][c]=s2[c]; }
  }
  __syncthreads();
  if (tid<4){
    float S =ls[0][tid]+ls[1][tid]+ls[2][tid]+ls[3][tid];
    float S2=ls2[0][tid]+ls2[1][tid]+ls2[2][tid]+ls2[3][tid];
    float mean = S*(1.0f/BB);
    float var  = S2*(1.0f/BB) - mean*mean;
    mean_out[c0+tid]=mean;
    rstd_out[c0+tid]=rsqrtf(var+1e-5f);
  }
}

// ---------------- Kernel 3: ego MLP, j-split 4 ways --------------------------
__global__ __launch_bounds__(256) void mlp_q_split(
    const float* __restrict__ x, const float* __restrict__ a,
    const float* __restrict__ W0, const float* __restrict__ b0,
    const float* __restrict__ W1, const float* __restrict__ b1,
    const float* __restrict__ W2,
    float* __restrict__ mlp_part)
{
  int bb = blockIdx.x*4;
  int js = blockIdx.y;            // 0..3 -> j in [js*100, js*100+100)
  int tid=threadIdx.x, wv=tid>>6, lane=tid&63;
  __shared__ float h1[4][HH];
  __shared__ float ego[4][4];
  if (tid<16){
    int bl=tid>>2, j=tid&3;
    int b=bb+bl;
    ego[bl][j] = (j<3) ? x[((size_t)b*NN)*8 + 4 + j] : a[b];
  }
  __syncthreads();
  for (int j=tid;j<HH;j+=256){
    float w0j[4];
    for (int i=0;i<4;i++) w0j[i]=W0[i*HH+j];
    for (int bl=0;bl<4;bl++){
      float v = b0[j];
      for (int i=0;i<4;i++) v += ego[bl][i]*w0j[i];
      h1[bl][j] = fmaxf(v, 0.0f);
    }
  }
  __syncthreads();
  float contrib[4]={0,0,0,0};
  if (tid < 100){
    int j = js*100 + tid;
    float a0=b1[j], a1=a0, a2=a0, a3=a0;
    const float* w1p = W1 + j;
    #pragma unroll 4
    for (int i=0;i<HH;i++){
      float w = w1p[(size_t)i*HH];
      a0 += h1[0][i]*w; a1 += h1[1][i]*w; a2 += h1[2][i]*w; a3 += h1[3][i]*w;
    }
    float w2 = W2[j];
    contrib[0]=fmaxf(a0,0.f)*w2; contrib[1]=fmaxf(a1,0.f)*w2;
    contrib[2]=fmaxf(a2,0.f)*w2; contrib[3]=fmaxf(a3,0.f)*w2;
  }
  __shared__ float red[4][4];
  for (int bl=0;bl<4;bl++) contrib[bl]=wave_sum(contrib[bl]);
  if (lane==0) for (int bl=0;bl<4;bl++) red[wv][bl]=contrib[bl];
  __syncthreads();
  if (tid<4){
    float s = red[0][tid]+red[1][tid]+red[2][tid]+red[3][tid];
    mlp_part[(size_t)(bb+tid)*4 + js] = s;
  }
}

// ---------------- Kernel 4: BN apply + one head per block (8 b, 1 k) ---------
__global__ __launch_bounds__(256) void heads_k(
    const float* __restrict__ t_buf, const float* __restrict__ mean_in,
    const float* __restrict__ rstd_in,
    const float* __restrict__ bn_g, const float* __restrict__ bn_b,
    const float* __restrict__ W3, const float* __restrict__ b3,
    const float* __restrict__ W4, const float* __restrict__ b4,
    float* __restrict__ headv_ws)
{
  int bb = blockIdx.x*8;          // 128 groups of 8 b
  int k  = blockIdx.y;            // 0..5
  int tid=threadIdx.x, wv=tid>>6, lane=tid&63;
  int t3 = k>>1;                  // which BN'd tensor (u/d/o)
  __shared__ float tn[8][200];
  for (int idx=tid; idx<1600; idx+=256){
    int bl=idx/200, v=idx-bl*200;
    int c = t3*200+v;
    tn[bl][v] = bn_g[v]*(t_buf[(size_t)(bb+bl)*600+c]-mean_in[c])*rstd_in[c]+bn_b[v];
  }
  __syncthreads();
  float contrib[8]={0,0,0,0,0,0,0,0};
  int g = tid;
  if (g < 200){
    float acc[8];
    float bias = b3[k*200+g];
    for (int bl=0;bl<8;bl++) acc[bl]=bias;
    const float* w3p = W3 + (size_t)k*40000 + g;
    #pragma unroll 4
    for (int v=0;v<200;v++){
      float w = w3p[(size_t)v*200];
      acc[0]+=tn[0][v]*w; acc[1]+=tn[1][v]*w;
      acc[2]+=tn[2][v]*w; acc[3]+=tn[3][v]*w;
      acc[4]+=tn[4][v]*w; acc[5]+=tn[5][v]*w;
      acc[6]+=tn[6][v]*w; acc[7]+=tn[7][v]*w;
    }
    float w4 = W4[k*200+g];
    for (int bl=0;bl<8;bl++){
      float h = acc[bl]>0.f ? acc[bl] : (expf(acc[bl])-1.0f);
      contrib[bl] = h*w4;
    }
  }
  for (int bl=0;bl<8;bl++) contrib[bl]=wave_sum(contrib[bl]);
  __shared__ float red[4][8];
  if (lane==0) for (int bl=0;bl<8;bl++) red[wv][bl]=contrib[bl];
  __syncthreads();
  if (tid<8){
    float s = red[0][tid]+red[1][tid]+red[2][tid]+red[3][tid];
    headv_ws[(size_t)(bb+tid)*6 + k] = s + b4[k];
  }
}

// ---------------- Kernel 5: finalize outputs ---------------------------------
__global__ __launch_bounds__(256) void finalize(
    const float* __restrict__ mlp_part, const float* __restrict__ headv_ws,
    const float* __restrict__ b2, float* __restrict__ out)
{
  int b = blockIdx.x*256 + threadIdx.x;   // grid 4
  if (b < BB){
    const float* mp = mlp_part + (size_t)b*4;
    float q = mp[0]+mp[1]+mp[2]+mp[3] + b2[0];
    const float* hv = headv_ws + (size_t)b*6;
    float A1 = hv[0]+hv[2]+hv[4];
    float A2 = hv[1]+hv[3]+hv[5];
    out[b]      = q;
    out[BB+b]   = A2;
    out[2*BB+b] = q+A1;
    out[3*BB+b] = q+A2;
    if (b==0) out[4*BB]=0.0f;
  }
}

extern "C" void kernel_launch(void* const* d_in, const int* in_sizes, int n_in,
                              void* d_out, int out_size, void* d_ws, size_t ws_size,
                              hipStream_t stream)
{
  (void)in_sizes; (void)n_in; (void)out_size; (void)ws_size;
  const float* merged=(const float*)d_in[0];
  const float* x     =(const float*)d_in[1];
  const float* a     =(const float*)d_in[2];
  const float* Wq_aug=(const float*)d_in[3];  const float* bq_aug=(const float*)d_in[4];
  const float* Wk_aug=(const float*)d_in[5];  const float* bk_aug=(const float*)d_in[6];
  const float* Wv_aug=(const float*)d_in[7];  const float* bv_aug=(const float*)d_in[8];
  const float* Wq_o  =(const float*)d_in[9];  const float* bq_o  =(const float*)d_in[10];
  const float* Wk_o  =(const float*)d_in[11]; const float* bk_o  =(const float*)d_in[12];
  const float* Wv_o  =(const float*)d_in[13]; const float* bv_o  =(const float*)d_in[14];
  const float* bn_g  =(const float*)d_in[15]; const float* bn_b  =(const float*)d_in[16];
  const float* W3    =(const float*)d_in[17]; const float* b3    =(const float*)d_in[18];
  const float* W4    =(const float*)d_in[19]; const float* b4    =(const float*)d_in[20];
  const float* W0    =(const float*)d_in[21]; const float* b0    =(const float*)d_in[22];
  const float* W1    =(const float*)d_in[23]; const float* b1    =(const float*)d_in[24];
  const float* W2    =(const float*)d_in[25]; const float* b2    =(const float*)d_in[26];

  float* out = (float*)d_out;
  float* ws  = (float*)d_ws;
  float* t_buf   = ws;             // 1024*600 = 614400 floats
  float* mean_b  = ws + 614400;    // 600
  float* rstd_b  = ws + 615000;    // 600
  float* mlp_part= ws + 615600;    // 1024*4 = 4096
  float* headv_ws= ws + 619696;    // 1024*6 = 6144

  hipLaunchKernelGGL(attn_kernel, dim3(BB), dim3(256), 0, stream, merged,
      Wq_aug,bq_aug,Wk_aug,bk_aug,Wv_aug,bv_aug,
      Wq_o,bq_o,Wk_o,bk_o,Wv_o,bv_o, t_buf);
  hipLaunchKernelGGL(mlp_q_split, dim3(BB/4,4), dim3(256), 0, stream,
      x,a,W0,b0,W1,b1,W2, mlp_part);
  hipLaunchKernelGGL(bn_stats, dim3(150), dim3(256), 0, stream,
      t_buf, mean_b, rstd_b);
  hipLaunchKernelGGL(heads_k, dim3(BB/8,6), dim3(256), 0, stream,
      t_buf, mean_b, rstd_b, bn_g, bn_b, W3, b3, W4, b4, headv_ws);
  hipLaunchKernelGGL(finalize, dim3(4), dim3(256), 0, stream,
      mlp_part, headv_ws, b2, out);
}

// Round 3
// 79.830 us; speedup vs baseline: 1.5396x; 1.0440x over previous
//
#include <hip/hip_runtime.h>

#define BB 1024
#define NN 128
#define VV 200
#define HH 400

__device__ inline float wave_sum(float v){
  for (int o=32;o>0;o>>=1) v += __shfl_down(v,o);
  return v;
}
__device__ inline float wave_max(float v){
  for (int o=32;o>0;o>>=1) v = fmaxf(v, __shfl_down(v,o));
  return v;
}

// ---------------- Kernel 1: per-b attention (algebraically reduced) ----------
// Also computes ego-MLP layer 0 (h1 = relu(ego4 @ W0 + b0)) into h1_buf.
__global__ __launch_bounds__(256) void attn_kernel(
    const float* __restrict__ merged,
    const float* __restrict__ x, const float* __restrict__ a,
    const float* __restrict__ W0, const float* __restrict__ b0,
    const float* __restrict__ Wq_aug, const float* __restrict__ bq_aug,
    const float* __restrict__ Wk_aug, const float* __restrict__ bk_aug,
    const float* __restrict__ Wv_aug, const float* __restrict__ bv_aug,
    const float* __restrict__ Wq_o,  const float* __restrict__ bq_o,
    const float* __restrict__ Wk_o,  const float* __restrict__ bk_o,
    const float* __restrict__ Wv_o,  const float* __restrict__ bv_o,
    float* __restrict__ t_buf, float* __restrict__ h1_buf)
{
  int b = blockIdx.x;
  int tid = threadIdx.x;
  int wv = tid>>6, lane = tid&63;
  const float* base = merged + (size_t)b*NN*15;

  __shared__ float q_aug[VV], q_o[VV];
  __shared__ float wkq_aug[14], wkq_o[7];
  __shared__ float qbk_aug_s, qbk_o_s;
  __shared__ float kv[NN*14];
  __shared__ float s_aug[NN], s_o[NN];
  __shared__ float wgt[3][NN];
  __shared__ unsigned char msk[3][NN];
  __shared__ float wf[3][14];
  __shared__ int anyf[3];
  __shared__ int w0cnt;

  float sub_bus = base[0];
  float sub_loc = base[2];

  // ego-MLP layer 0 (independent folded-in work)
  {
    const float* xb = x + (size_t)b*NN*8;
    float e0 = xb[4], e1 = xb[5], e2 = xb[6], e3 = a[b];
    for (int i=tid;i<HH;i+=256){
      float v = b0[i] + e0*W0[0*HH+i] + e1*W0[1*HH+i]
                      + e2*W0[2*HH+i] + e3*W0[3*HH+i];
      h1_buf[(size_t)b*HH+i] = fmaxf(v, 0.0f);
    }
  }

  // q projections (ego7[0] == 0 after the sub_bus subtraction)
  if (tid < VV) {
    float qa = bq_aug[tid], qo = bq_o[tid];
    for (int j=1;j<7;j++){
      float e = base[j];
      qa += e * Wq_aug[j*VV+tid];
      qo += e * Wq_o[j*VV+tid];
    }
    q_aug[tid]=qa; q_o[tid]=qo;
  }
  __syncthreads();

  // fold Wk into q: 23 reductions of length 200
  for (int r=wv; r<23; r+=4){
    const float* coef; const float* qv;
    if (r<14)      { coef = Wk_aug + r*VV;      qv = q_aug; }
    else if (r==14){ coef = bk_aug;             qv = q_aug; }
    else if (r<22) { coef = Wk_o + (r-15)*VV;   qv = q_o;   }
    else           { coef = bk_o;               qv = q_o;   }
    float p=0;
    for (int d=lane; d<VV; d+=64) p += coef[d]*qv[d];
    p = wave_sum(p);
    if (lane==0){
      if (r<14) wkq_aug[r]=p;
      else if (r==14) qbk_aug_s=p;
      else if (r<22) wkq_o[r-15]=p;
      else qbk_o_s=p;
    }
  }
  __syncthreads();

  // per-n scores & masks
  const float scale = 0.07071067811865475f; // 1/sqrt(200)
  bool f0=false;
  int prior = 0;
  if (tid < NN){
    float m[15];
    for (int i=0;i<15;i++) m[i] = base[tid*15+i];
    m[0]-=sub_bus; m[7]-=sub_bus;
    for (int f=0;f<14;f++) kv[tid*14+f]=m[f];
    float flag=m[14], loc=m[2];
    f0 = (flag==0.0f);
    bool um = (loc<sub_loc) && (flag==1.0f);
    bool dm = (loc>sub_loc) && (flag==1.0f);
    float sa = qbk_aug_s, so = qbk_o_s;
    for (int f=0;f<14;f++) sa += m[f]*wkq_aug[f];
    for (int f=0;f<7;f++)  so += m[f]*wkq_o[f];
    s_aug[tid]=sa*scale; s_o[tid]=so*scale;
    msk[0][tid]=um; msk[1][tid]=dm;
    unsigned long long bal = __ballot(f0);
    prior = __popcll(bal & ((1ull<<lane)-1ull));
    if (tid==0) w0cnt = __popcll(bal);
  }
  __syncthreads();
  if (tid < NN){
    int ptot = prior + (wv==1 ? w0cnt : 0);
    msk[2][tid] = (unsigned char)(f0 && (ptot>0));
  }
  __syncthreads();

  // masked softmax, one wave per mask
  if (wv < 3){
    const float* sarr = (wv==2)? s_o : s_aug;
    float mx=-3e38f;
    for (int i=lane;i<NN;i+=64) if (msk[wv][i]) mx = fmaxf(mx, sarr[i]);
    mx = wave_max(mx);
    mx = __shfl(mx, 0);
    float sum=0;
    for (int i=lane;i<NN;i+=64) if (msk[wv][i]) sum += expf(sarr[i]-mx);
    sum = wave_sum(sum);
    sum = __shfl(sum, 0);
    int any = (mx > -1e38f) ? 1 : 0;
    float inv = any ? 1.0f/sum : 0.0f;
    for (int i=lane;i<NN;i+=64)
      wgt[wv][i] = msk[wv][i] ? expf(sarr[i]-mx)*inv : 0.0f;
    if (lane==0) anyf[wv]=any;
  }
  __syncthreads();

  // weighted feature sums: 35 reductions of length 128
  for (int r=wv; r<35; r+=4){
    int mi, f;
    if (r<14){mi=0;f=r;} else if (r<28){mi=1;f=r-14;} else {mi=2;f=r-28;}
    float p=0;
    for (int n=lane;n<NN;n+=64) p += wgt[mi][n]*kv[n*14+f];
    p=wave_sum(p);
    if (lane==0) wf[mi][f]=p;
  }
  __syncthreads();

  // project to V=200 through Wv
  if (tid < VV){
    float uv=bv_aug[tid], dv=bv_aug[tid], ov=bv_o[tid];
    for (int f=0;f<14;f++){
      float w = Wv_aug[f*VV+tid];
      uv += wf[0][f]*w;
      dv += wf[1][f]*w;
    }
    for (int f=0;f<7;f++) ov += wf[2][f]*Wv_o[f*VV+tid];
    if (!anyf[0]) uv=0.0f;
    if (!anyf[1]) dv=0.0f;
    if (!anyf[2]) ov=0.0f;
    float* tb = t_buf + (size_t)b*600;
    tb[tid]=uv; tb[200+tid]=dv; tb[400+tid]=ov;
  }
}

// ---------------- Kernel 2: BN stats over batch (float4, each elem once) -----
__global__ __launch_bounds__(256) void bn_stats(const float* __restrict__ t_buf,
    float* __restrict__ mean_out, float* __restrict__ rstd_out)
{
  int c0 = blockIdx.x*4;          // 150 blocks x 4 channels
  int tid=threadIdx.x; int wv=tid>>6, lane=tid&63;
  float s[4]={0,0,0,0}, s2[4]={0,0,0,0};
  for (int b=tid;b<BB;b+=256){
    float4 v = *reinterpret_cast<const float4*>(t_buf + (size_t)b*600 + c0);
    s[0]+=v.x; s[1]+=v.y; s[2]+=v.z; s[3]+=v.w;
    s2[0]+=v.x*v.x; s2[1]+=v.y*v.y; s2[2]+=v.z*v.z; s2[3]+=v.w*v.w;
  }
  __shared__ float ls[4][4], ls2[4][4];
  for (int c=0;c<4;c++){ s[c]=wave_sum(s[c]); s2[c]=wave_sum(s2[c]); }
  if (lane==0){
    for (int c=0;c<4;c++){ ls[wv][c]=s[c]; ls2[wv][c]=s2[c]; }
  }
  __syncthreads();
  if (tid<4){
    float S =ls[0][tid]+ls[1][tid]+ls[2][tid]+ls[3][tid];
    float S2=ls2[0][tid]+ls2[1][tid]+ls2[2][tid]+ls2[3][tid];
    float mean = S*(1.0f/BB);
    float var  = S2*(1.0f/BB) - mean*mean;
    mean_out[c0+tid]=mean;
    rstd_out[c0+tid]=rsqrtf(var+1e-5f);
  }
}

// ---------------- Kernel 3: ego MLP layer1+2, fully parallel -----------------
__global__ __launch_bounds__(256) void mlp_q_v2(
    const float* __restrict__ h1_buf,
    const float* __restrict__ W1, const float* __restrict__ b1,
    const float* __restrict__ W2,
    float* __restrict__ mlp_part)
{
  int bb = blockIdx.x*8;
  int js = blockIdx.y;            // 0..6
  int tid=threadIdx.x;
  int jl = tid & 63;
  int ic = tid >> 6;              // 0..3
  int j  = js*64 + jl;
  bool jok = (j < HH);
  int jc = jok ? j : (HH-1);

  float acc[8]={0,0,0,0,0,0,0,0};
  {
    const float* w1p = W1 + jc;
    const float* h0 = h1_buf + (size_t)(bb+0)*HH;
    const float* h1 = h1_buf + (size_t)(bb+1)*HH;
    const float* h2 = h1_buf + (size_t)(bb+2)*HH;
    const float* h3 = h1_buf + (size_t)(bb+3)*HH;
    const float* h4 = h1_buf + (size_t)(bb+4)*HH;
    const float* h5 = h1_buf + (size_t)(bb+5)*HH;
    const float* h6 = h1_buf + (size_t)(bb+6)*HH;
    const float* h7 = h1_buf + (size_t)(bb+7)*HH;
    int i0 = ic*100;
    #pragma unroll 4
    for (int i=i0;i<i0+100;i++){
      float w = w1p[(size_t)i*HH];
      acc[0]+=h0[i]*w; acc[1]+=h1[i]*w; acc[2]+=h2[i]*w; acc[3]+=h3[i]*w;
      acc[4]+=h4[i]*w; acc[5]+=h5[i]*w; acc[6]+=h6[i]*w; acc[7]+=h7[i]*w;
    }
  }
  __shared__ float part[4][64][9];   // pad 9 -> benign 2-way bank alias
  for (int bl=0;bl<8;bl++) part[ic][jl][bl]=acc[bl];
  __syncthreads();
  if (tid < 64){
    float bj = b1[jc], w2 = W2[jc];
    for (int bl=0;bl<8;bl++){
      float s = part[0][jl][bl]+part[1][jl][bl]+part[2][jl][bl]+part[3][jl][bl];
      s += bj;
      float contrib = jok ? fmaxf(s, 0.0f)*w2 : 0.0f;
      float tot = wave_sum(contrib);
      if (jl==0) mlp_part[(size_t)(bb+bl)*8 + js] = tot;
    }
  }
}

// ---------------- Kernel 4: BN apply + one head per block (8 b, 1 k) ---------
__global__ __launch_bounds__(256) void heads_k(
    const float* __restrict__ t_buf, const float* __restrict__ mean_in,
    const float* __restrict__ rstd_in,
    const float* __restrict__ bn_g, const float* __restrict__ bn_b,
    const float* __restrict__ W3, const float* __restrict__ b3,
    const float* __restrict__ W4, const float* __restrict__ b4,
    float* __restrict__ headv_ws)
{
  int bb = blockIdx.x*8;          // 128 groups of 8 b
  int k  = blockIdx.y;            // 0..5
  int tid=threadIdx.x, wv=tid>>6, lane=tid&63;
  int t3 = k>>1;                  // which BN'd tensor (u/d/o)
  __shared__ float tn[8][200];
  for (int idx=tid; idx<1600; idx+=256){
    int bl=idx/200, v=idx-bl*200;
    int c = t3*200+v;
    tn[bl][v] = bn_g[v]*(t_buf[(size_t)(bb+bl)*600+c]-mean_in[c])*rstd_in[c]+bn_b[v];
  }
  __syncthreads();
  float contrib[8]={0,0,0,0,0,0,0,0};
  int g = tid;
  if (g < 200){
    float acc[8];
    float bias = b3[k*200+g];
    for (int bl=0;bl<8;bl++) acc[bl]=bias;
    const float* w3p = W3 + (size_t)k*40000 + g;
    #pragma unroll 4
    for (int v=0;v<200;v++){
      float w = w3p[(size_t)v*200];
      acc[0]+=tn[0][v]*w; acc[1]+=tn[1][v]*w;
      acc[2]+=tn[2][v]*w; acc[3]+=tn[3][v]*w;
      acc[4]+=tn[4][v]*w; acc[5]+=tn[5][v]*w;
      acc[6]+=tn[6][v]*w; acc[7]+=tn[7][v]*w;
    }
    float w4 = W4[k*200+g];
    for (int bl=0;bl<8;bl++){
      float h = acc[bl]>0.f ? acc[bl] : (expf(acc[bl])-1.0f);
      contrib[bl] = h*w4;
    }
  }
  for (int bl=0;bl<8;bl++) contrib[bl]=wave_sum(contrib[bl]);
  __shared__ float red[4][8];
  if (lane==0) for (int bl=0;bl<8;bl++) red[wv][bl]=contrib[bl];
  __syncthreads();
  if (tid<8){
    float s = red[0][tid]+red[1][tid]+red[2][tid]+red[3][tid];
    headv_ws[(size_t)(bb+tid)*6 + k] = s + b4[k];
  }
}

// ---------------- Kernel 5: finalize outputs ---------------------------------
__global__ __launch_bounds__(256) void finalize(
    const float* __restrict__ mlp_part, const float* __restrict__ headv_ws,
    const float* __restrict__ b2, float* __restrict__ out)
{
  int b = blockIdx.x*256 + threadIdx.x;   // grid 4
  if (b < BB){
    const float* mp = mlp_part + (size_t)b*8;
    float q = mp[0]+mp[1]+mp[2]+mp[3]+mp[4]+mp[5]+mp[6] + b2[0];
    const float* hv = headv_ws + (size_t)b*6;
    float A1 = hv[0]+hv[2]+hv[4];
    float A2 = hv[1]+hv[3]+hv[5];
    out[b]      = q;
    out[BB+b]   = A2;
    out[2*BB+b] = q+A1;
    out[3*BB+b] = q+A2;
    if (b==0) out[4*BB]=0.0f;
  }
}

extern "C" void kernel_launch(void* const* d_in, const int* in_sizes, int n_in,
                              void* d_out, int out_size, void* d_ws, size_t ws_size,
                              hipStream_t stream)
{
  (void)in_sizes; (void)n_in; (void)out_size; (void)ws_size;
  const float* merged=(const float*)d_in[0];
  const float* x     =(const float*)d_in[1];
  const float* a     =(const float*)d_in[2];
  const float* Wq_aug=(const float*)d_in[3];  const float* bq_aug=(const float*)d_in[4];
  const float* Wk_aug=(const float*)d_in[5];  const float* bk_aug=(const float*)d_in[6];
  const float* Wv_aug=(const float*)d_in[7];  const float* bv_aug=(const float*)d_in[8];
  const float* Wq_o  =(const float*)d_in[9];  const float* bq_o  =(const float*)d_in[10];
  const float* Wk_o  =(const float*)d_in[11]; const float* bk_o  =(const float*)d_in[12];
  const float* Wv_o  =(const float*)d_in[13]; const float* bv_o  =(const float*)d_in[14];
  const float* bn_g  =(const float*)d_in[15]; const float* bn_b  =(const float*)d_in[16];
  const float* W3    =(const float*)d_in[17]; const float* b3    =(const float*)d_in[18];
  const float* W4    =(const float*)d_in[19]; const float* b4    =(const float*)d_in[20];
  const float* W0    =(const float*)d_in[21]; const float* b0    =(const float*)d_in[22];
  const float* W1    =(const float*)d_in[23]; const float* b1    =(const float*)d_in[24];
  const float* W2    =(const float*)d_in[25]; const float* b2    =(const float*)d_in[26];

  float* out = (float*)d_out;
  float* ws  = (float*)d_ws;
  float* t_buf   = ws;             // 1024*600 = 614400 floats
  float* mean_b  = ws + 614400;    // 600
  float* rstd_b  = ws + 615000;    // 600
  float* mlp_part= ws + 615600;    // 1024*8 = 8192
  float* headv_ws= ws + 623792;    // 1024*6 = 6144
  float* h1_buf  = ws + 629936;    // 1024*400 = 409600

  hipLaunchKernelGGL(attn_kernel, dim3(BB), dim3(256), 0, stream, merged,
      x, a, W0, b0,
      Wq_aug,bq_aug,Wk_aug,bk_aug,Wv_aug,bv_aug,
      Wq_o,bq_o,Wk_o,bk_o,Wv_o,bv_o, t_buf, h1_buf);
  hipLaunchKernelGGL(mlp_q_v2, dim3(BB/8,7), dim3(256), 0, stream,
      h1_buf, W1, b1, W2, mlp_part);
  hipLaunchKernelGGL(bn_stats, dim3(150), dim3(256), 0, stream,
      t_buf, mean_b, rstd_b);
  hipLaunchKernelGGL(heads_k, dim3(BB/8,6), dim3(256), 0, stream,
      t_buf, mean_b, rstd_b, bn_g, bn_b, W3, b3, W4, b4, headv_ws);
  hipLaunchKernelGGL(finalize, dim3(4), dim3(256), 0, stream,
      mlp_part, headv_ws, b2, out);
}